// Round 1
// baseline (924.448 us; speedup 1.0000x reference)
//
#include <hip/hip_runtime.h>
#include <cstdint>

// Masks packed as 36-bit fields, bit index = (h%6)*6 + (w%6).
// R_POS -> bits {4,6,8,16,19,27,29,31} = 0xA8090150
// B_POS -> bits {1,9,11,13,22,24,26,34} = 0x405402A02
#define RBITS 0xA8090150ULL
#define BBITS 0x405402A02ULL

#define IMG_H 1536
#define IMG_W 1536
#define TB 128   // threads per block; W/4 = 384 = 3 * 128

__global__ __launch_bounds__(TB) void xflat_rgb_extract(
    const float* __restrict__ green,
    const float* __restrict__ xtrans,
    const float* __restrict__ chroma,
    float* __restrict__ out)
{
    const int w4 = blockIdx.x * TB + threadIdx.x;   // float4 index along W
    const int h  = blockIdx.y;
    const int b  = blockIdx.z;
    const int w  = w4 * 4;

    const long plane = (long)IMG_H * IMG_W;
    const long poff  = (long)h * IMG_W + w;

    const float4 g  = *(const float4*)(green  + (long)b * plane          + poff);
    const float4 x0 = *(const float4*)(xtrans + ((long)b * 3 + 0) * plane + poff);
    const float4 x2 = *(const float4*)(xtrans + ((long)b * 3 + 2) * plane + poff);
    const float4 c0 = *(const float4*)(chroma + ((long)b * 2 + 0) * plane + poff);
    const float4 c1 = *(const float4*)(chroma + ((long)b * 2 + 1) * plane + poff);

    const int base = (h % 6) * 6;   // wave-uniform (h is blockIdx.y)
    int wj = w % 6;

    float4 o0, o2;

    o0.x = ((RBITS >> (base + wj)) & 1) ? x0.x : c0.x;
    o2.x = ((BBITS >> (base + wj)) & 1) ? x2.x : c1.x;
    wj++; if (wj == 6) wj = 0;

    o0.y = ((RBITS >> (base + wj)) & 1) ? x0.y : c0.y;
    o2.y = ((BBITS >> (base + wj)) & 1) ? x2.y : c1.y;
    wj++; if (wj == 6) wj = 0;

    o0.z = ((RBITS >> (base + wj)) & 1) ? x0.z : c0.z;
    o2.z = ((BBITS >> (base + wj)) & 1) ? x2.z : c1.z;
    wj++; if (wj == 6) wj = 0;

    o0.w = ((RBITS >> (base + wj)) & 1) ? x0.w : c0.w;
    o2.w = ((BBITS >> (base + wj)) & 1) ? x2.w : c1.w;

    float* ob = out + ((long)b * 3) * plane + poff;
    *(float4*)(ob)             = o0;   // channel 0
    *(float4*)(ob + plane)     = g;    // channel 1 (green passthrough)
    *(float4*)(ob + 2 * plane) = o2;   // channel 2
}

extern "C" void kernel_launch(void* const* d_in, const int* in_sizes, int n_in,
                              void* d_out, int out_size, void* d_ws, size_t ws_size,
                              hipStream_t stream) {
    const float* green  = (const float*)d_in[0];  // (16,1,1536,1536)
    const float* xtrans = (const float*)d_in[1];  // (16,3,1536,1536)
    const float* chroma = (const float*)d_in[2];  // (16,2,1536,1536)
    float* out = (float*)d_out;                   // (16,3,1536,1536)

    dim3 grid(IMG_W / 4 / TB, IMG_H, 16);
    dim3 block(TB);
    xflat_rgb_extract<<<grid, block, 0, stream>>>(green, xtrans, chroma, out);
}